// Round 2
// baseline (789.672 us; speedup 1.0000x reference)
//
#include <hip/hip_runtime.h>
#include <cstdint>
#include <cstddef>

// TrimodalCrossAttention: seq_len=1 => softmax==1 => attention i reduces to
//   att_i(kv) = kv @ (Wo_i@Wv_i)^T + (Wo_i@bv_i + bo_i)
// Whole model folds to: out = relu([g|d|c] @ A + bias_h) @ W2^T + b2,
// A [768,512] from W1 and Wf_i = Wo_i@Wv_i.
//
// k_main v2: barrier-free stage-1. A-frags (X) loaded direct from global in
// MFMA A-layout (dense 16-line loads), cvt fp32->bf16 in-register
// (round-half-up + v_perm pack). B-frags loaded direct from fragment-ordered
// ATS in L2. No LDS, no __syncthreads in the K-loop.

typedef __attribute__((ext_vector_type(8))) short short8;
typedef __attribute__((ext_vector_type(4))) float float4v;

__device__ __forceinline__ unsigned short f2bf(float f) {
  union { float f; unsigned u; } v; v.f = f;
  unsigned r = v.u + 0x7FFFu + ((v.u >> 16) & 1u);   // RNE
  return (unsigned short)(r >> 16);
}

// ---------------- P0: Wf[i] = Wo[i] @ Wv[i]  (6x 256x256x256 fp32) ----------
// 4 rows per block -> 4 independent acc chains, Wv column loads shared.
__global__ __launch_bounds__(256) void k_wf(const float* __restrict__ Wo,
                                            const float* __restrict__ Wv,
                                            float* __restrict__ Wf) {
  int b = blockIdx.x;              // 0..383
  int i = b >> 6, m0 = (b & 63) * 4;
  int n = threadIdx.x;
  const float* wo = Wo + i * 65536 + m0 * 256;   // rows m0..m0+3 (uniform -> s_load)
  const float* wvp = Wv + i * 65536 + n;         // column n (coalesced)
  float a0 = 0.f, a1 = 0.f, a2 = 0.f, a3 = 0.f;
#pragma unroll 4
  for (int k = 0; k < 256; ++k) {
    float wvv = wvp[k * 256];
    a0 += wo[k] * wvv;
    a1 += wo[256 + k] * wvv;
    a2 += wo[512 + k] * wvv;
    a3 += wo[768 + k] * wvv;
  }
  float* out = Wf + i * 65536 + m0 * 256 + n;
  out[0] = a0; out[256] = a1; out[512] = a2; out[768] = a3;
}

// ---------------- P0b: bfs[p][m] = Wo_{2p}[m,:]@bv_{2p} + Wo_{2p+1}[m,:]@bv_{2p+1} + bo terms
// wave-per-row, float4 coalesced + shuffle reduce.
__global__ __launch_bounds__(256) void k_bf(const float* __restrict__ Wo,
                                            const float* __restrict__ bv,
                                            const float* __restrict__ bo,
                                            float* __restrict__ bfs) {
  int p = blockIdx.x;              // 0:g 1:d 2:c
  int a = 2 * p, bb = 2 * p + 1;
  int wave = threadIdx.x >> 6, lane = threadIdx.x & 63;
  float4v bva = *(const float4v*)(bv + a * 256 + lane * 4);
  float4v bvb = *(const float4v*)(bv + bb * 256 + lane * 4);
  for (int m = wave; m < 256; m += 4) {
    float4v ra = *(const float4v*)(Wo + a * 65536 + m * 256 + lane * 4);
    float4v rb = *(const float4v*)(Wo + bb * 65536 + m * 256 + lane * 4);
    float s = ra[0]*bva[0] + ra[1]*bva[1] + ra[2]*bva[2] + ra[3]*bva[3]
            + rb[0]*bvb[0] + rb[1]*bvb[1] + rb[2]*bvb[2] + rb[3]*bvb[3];
#pragma unroll
    for (int off = 32; off > 0; off >>= 1) s += __shfl_down(s, off);
    if (lane == 0) bfs[p * 256 + m] = s + bo[a * 256 + m] + bo[bb * 256 + m];
  }
}

// ---------------- P1: fold A[k][n], write fragment-ordered bf16 -------------
// ATS element index for (k,n): kt=k>>5, lq=(k>>3)&3, j8=k&7;
//   wn=n>>7, j=(n>>4)&7, l15=n&15;
//   idx = kt*16384 + (wn*8+j)*512 + (l15*4+lq)*8 + j8
__global__ __launch_bounds__(256) void k_fold(const float* __restrict__ W1,
                                              const float* __restrict__ Wf,
                                              unsigned short* __restrict__ ATS) {
  int b = blockIdx.x;              // 0..1535
  int n = b & 511, p = b >> 9;
  int kk = threadIdx.x;
  int fA, oA, fB, oB;
  if (p == 0)      { fA = 2; oA = 256; fB = 4; oB = 512; }   // dg, cg
  else if (p == 1) { fA = 0; oA = 0;   fB = 5; oB = 512; }   // gd, cd
  else             { fA = 1; oA = 0;   fB = 3; oB = 256; }   // gc, dc
  const float* w1n = W1 + n * 768;                // uniform -> s_load
  const float* wfa = Wf + fA * 65536 + kk;        // coalesced columns
  const float* wfb = Wf + fB * 65536 + kk;
  float v0 = w1n[p * 256 + kk], v1 = 0.f, v2 = 0.f, v3 = 0.f;
#pragma unroll 4
  for (int j = 0; j < 64; ++j) {
    v0 += w1n[oA + j]       * wfa[j * 256]         + w1n[oB + j]       * wfb[j * 256];
    v1 += w1n[oA + 64 + j]  * wfa[(64 + j) * 256]  + w1n[oB + 64 + j]  * wfb[(64 + j) * 256];
    v2 += w1n[oA + 128 + j] * wfa[(128 + j) * 256] + w1n[oB + 128 + j] * wfb[(128 + j) * 256];
    v3 += w1n[oA + 192 + j] * wfa[(192 + j) * 256] + w1n[oB + 192 + j] * wfb[(192 + j) * 256];
  }
  float val = (v0 + v1) + (v2 + v3);
  int k = p * 256 + kk;
  int kt = k >> 5, lq = (k >> 3) & 3, j8 = k & 7;
  int wn = n >> 7, j = (n >> 4) & 7, l15 = n & 15;
  ATS[kt * 16384 + (wn * 8 + j) * 512 + (l15 * 4 + lq) * 8 + j8] = f2bf(val);
}

// ---------------- P1b: bias_h[n] = b1[n] + sum_k W1[n][k]*bfs[k] ------------
__global__ __launch_bounds__(256) void k_biash(const float* __restrict__ W1,
                                               const float* __restrict__ b1,
                                               const float* __restrict__ bfs,
                                               float* __restrict__ bias_h) {
  int n = blockIdx.x;              // 0..511
  int kk = threadIdx.x;
  const float* w1n = W1 + n * 768;
  float v = w1n[kk] * bfs[kk] + w1n[256 + kk] * bfs[256 + kk] +
            w1n[512 + kk] * bfs[512 + kk];
  __shared__ float red[256];
  red[kk] = v; __syncthreads();
  for (int s = 128; s > 0; s >>= 1) { if (kk < s) red[kk] += red[kk + s]; __syncthreads(); }
  if (kk == 0) bias_h[n] = red[0] + b1[n];
}

// ---------------- P2: W2 -> bf16, fragment-ordered for stage-2 --------------
// W2p[(k>>5)*8192 + n*32 + (k&31)] = bf16(W2[n][k])
__global__ __launch_bounds__(256) void k_w2(const float* __restrict__ W2,
                                            unsigned short* __restrict__ W2p) {
  int id = blockIdx.x * 256 + threadIdx.x;       // 0..131071
  int kt2 = id >> 13;
  int rem = id & 8191;
  int n = rem >> 5, klo = rem & 31;
  W2p[id] = f2bf(W2[n * 512 + kt2 * 32 + klo]);
}

// ---------------- Main fused kernel -----------------------------------------
// 512 threads = 8 waves (wm 0..1 x wn 0..3), block = 128 rows x N=512 hidden.
// Stage 1: barrier-free. Stage 2: 4 hidden chunks of 128 via LDS.
__global__ __launch_bounds__(512, 1) void k_main(
    const float* __restrict__ G, const float* __restrict__ D,
    const float* __restrict__ C, const unsigned short* __restrict__ ATS,
    const float* __restrict__ bias_h, const unsigned short* __restrict__ W2p,
    const float* __restrict__ b2, float* __restrict__ Out) {
  __shared__ unsigned short hid[128][136];   // 34.8 KB, 128 rows x 128-col chunk (+8 pad)

  const int tid = threadIdx.x;
  const int lane = tid & 63, wave = tid >> 6;
  const int l15 = lane & 15, lq = lane >> 4;
  const int m0 = blockIdx.x * 128;
  const int wm = wave >> 2, wn = wave & 3;

  // ---- stage 1 accumulators (bias-initialized) ----
  float4v acc1[4][8];
#pragma unroll
  for (int j = 0; j < 8; ++j) {
    float bh = bias_h[wn * 128 + j * 16 + l15];
#pragma unroll
    for (int i = 0; i < 4; ++i) acc1[i][j] = (float4v){bh, bh, bh, bh};
  }

  // per-lane row offsets for A-frag loads (MFMA A-layout: row=l15, k=lq*8+j8)
  size_t roff[4];
#pragma unroll
  for (int i = 0; i < 4; ++i)
    roff[i] = (size_t)(m0 + wm * 64 + i * 16 + l15) * 256 + lq * 8;

  float4v fa[4][2];
  {
    const float* S = G;
#pragma unroll
    for (int i = 0; i < 4; ++i) {
      const float* p = S + roff[i];
      fa[i][0] = *(const float4v*)p;
      fa[i][1] = *(const float4v*)(p + 4);
    }
  }

  const unsigned short* bbase = ATS + (wn * 8) * 512 + (l15 * 4 + lq) * 8;

  for (int kt = 0; kt < 24; ++kt) {
    // convert current fa -> bf16 A-frags (round-half-up + perm pack)
    short8 af[4];
#pragma unroll
    for (int i = 0; i < 4; ++i) {
      union { float4v f; unsigned u[4]; } s0, s1;
      s0.f = fa[i][0]; s1.f = fa[i][1];
      union { short8 s; unsigned u[4]; } r;
      r.u[0] = __builtin_amdgcn_perm(s0.u[1] + 0x8000u, s0.u[0] + 0x8000u, 0x07060302u);
      r.u[1] = __builtin_amdgcn_perm(s0.u[3] + 0x8000u, s0.u[2] + 0x8000u, 0x07060302u);
      r.u[2] = __builtin_amdgcn_perm(s1.u[1] + 0x8000u, s1.u[0] + 0x8000u, 0x07060302u);
      r.u[3] = __builtin_amdgcn_perm(s1.u[3] + 0x8000u, s1.u[2] + 0x8000u, 0x07060302u);
      af[i] = r.s;
    }
    // prefetch next k-window (HBM) — no barrier, loads stay in flight over MFMAs
    if (kt < 23) {
      int kn = kt + 1;
      const float* S = (kn < 8) ? G : (kn < 16) ? D : C;
      const float* base = S + ((kn * 32) & 255);
#pragma unroll
      for (int i = 0; i < 4; ++i) {
        const float* p = base + roff[i];
        fa[i][0] = *(const float4v*)p;
        fa[i][1] = *(const float4v*)(p + 4);
      }
    }
    // B-frags direct from L2 (fragment-ordered ATS)
    const unsigned short* bp = bbase + kt * 16384;
    short8 bfr[8];
#pragma unroll
    for (int j = 0; j < 8; ++j) bfr[j] = *(const short8*)(bp + j * 512);
#pragma unroll
    for (int j = 0; j < 8; ++j)
#pragma unroll
      for (int i = 0; i < 4; ++i)
        acc1[i][j] = __builtin_amdgcn_mfma_f32_16x16x32_bf16(af[i], bfr[j], acc1[i][j], 0, 0, 0);
  }

  // ---- stage 2: out[128][256] = relu(hidden) @ W2^T + b2 ----
  const int om = wave >> 2, on = wave & 3;   // out tile: rows om*64, cols on*64
  float4v acc2[4][4];
#pragma unroll
  for (int j = 0; j < 4; ++j) {
    float bbv = b2[on * 64 + j * 16 + l15];
#pragma unroll
    for (int i = 0; i < 4; ++i) acc2[i][j] = (float4v){bbv, bbv, bbv, bbv};
  }

  for (int cpos = 0; cpos < 4; ++cpos) {
    if (wn == cpos) {   // this wave's 128 hidden cols == chunk cpos
#pragma unroll
      for (int j = 0; j < 8; ++j)
#pragma unroll
        for (int i = 0; i < 4; ++i)
#pragma unroll
          for (int r = 0; r < 4; ++r) {
            float v = acc1[i][j][r];
            v = v > 0.f ? v : 0.f;
            union { float f; unsigned u; } cv; cv.f = v;
            hid[wm * 64 + i * 16 + lq * 4 + r][j * 16 + l15] =
                (unsigned short)((cv.u + 0x8000u) >> 16);
          }
    }
    __syncthreads();
#pragma unroll
    for (int ks = 0; ks < 4; ++ks) {
      short8 a2[4];
#pragma unroll
      for (int i = 0; i < 4; ++i)
        a2[i] = *(const short8*)&hid[om * 64 + i * 16 + l15][ks * 32 + lq * 8];
#pragma unroll
      for (int j = 0; j < 4; ++j) {
        const unsigned short* bp = W2p + (size_t)(cpos * 4 + ks) * 8192 +
                                   (on * 64 + j * 16 + l15) * 32 + lq * 8;
        short8 bfrag = *(const short8*)bp;
#pragma unroll
        for (int i = 0; i < 4; ++i)
          acc2[i][j] = __builtin_amdgcn_mfma_f32_16x16x32_bf16(a2[i], bfrag, acc2[i][j], 0, 0, 0);
      }
    }
    __syncthreads();
  }

  // epilogue: fp32 stores
#pragma unroll
  for (int i = 0; i < 4; ++i)
#pragma unroll
    for (int r = 0; r < 4; ++r) {
      int row = m0 + om * 64 + i * 16 + lq * 4 + r;
      float* op = Out + (size_t)row * 256 + on * 64 + l15;
#pragma unroll
      for (int j = 0; j < 4; ++j) op[j * 16] = acc2[i][j][r];
    }
}

// ---------------- launcher ---------------------------------------------------
extern "C" void kernel_launch(void* const* d_in, const int* in_sizes, int n_in,
                              void* d_out, int out_size, void* d_ws, size_t ws_size,
                              hipStream_t stream) {
  const float* G  = (const float*)d_in[0];
  const float* D  = (const float*)d_in[1];
  const float* C  = (const float*)d_in[2];
  // d_in[3]=Wq, d_in[4]=Wk, d_in[6]=bq, d_in[7]=bk unused: softmax over 1 key == 1
  const float* Wv = (const float*)d_in[5];
  const float* bv = (const float*)d_in[8];
  const float* Wo = (const float*)d_in[9];
  const float* bo = (const float*)d_in[10];
  const float* W1 = (const float*)d_in[11];
  const float* b1 = (const float*)d_in[12];
  const float* W2 = (const float*)d_in[13];
  const float* b2 = (const float*)d_in[14];

  char* ws = (char*)d_ws;
  float* Wf           = (float*)(ws);                       // 1,572,864 B
  float* bfs          = (float*)(ws + 1572864);             //     3,072 B
  float* bias_h       = (float*)(ws + 1575936);             //     2,048 B
  unsigned short* ATS = (unsigned short*)(ws + 1577984);    //   786,432 B
  unsigned short* W2p = (unsigned short*)(ws + 2364416);    //   262,144 B
  float* Out = (float*)d_out;

  hipLaunchKernelGGL(k_wf,    dim3(384),  dim3(256), 0, stream, Wo, Wv, Wf);
  hipLaunchKernelGGL(k_bf,    dim3(3),    dim3(256), 0, stream, Wo, bv, bo, bfs);
  hipLaunchKernelGGL(k_fold,  dim3(1536), dim3(256), 0, stream, W1, Wf, ATS);
  hipLaunchKernelGGL(k_biash, dim3(512),  dim3(256), 0, stream, W1, b1, bfs, bias_h);
  hipLaunchKernelGGL(k_w2,    dim3(512),  dim3(256), 0, stream, W2, W2p);
  hipLaunchKernelGGL(k_main,  dim3(1024), dim3(512), 0, stream, G, D, C, ATS, bias_h, W2p, b2, Out);
}